// Round 9
// baseline (375.239 us; speedup 1.0000x reference)
//
#include <hip/hip_runtime.h>

typedef float  f32x4  __attribute__((ext_vector_type(4)));
typedef __bf16 bf16x8 __attribute__((ext_vector_type(8)));
typedef __bf16 bf16x4 __attribute__((ext_vector_type(4)));
typedef unsigned short u16x8 __attribute__((ext_vector_type(8)));

__device__ __forceinline__ unsigned short f2bf(float f) {
    unsigned u = __builtin_bit_cast(unsigned, f);
    unsigned r = u + 0x7FFFu + ((u >> 16) & 1u);   // round-to-nearest-even
    return (unsigned short)(r >> 16);
}

__device__ __forceinline__ f32x4 mfma16(bf16x8 a, bf16x8 b, f32x4 c) {
    return __builtin_amdgcn_mfma_f32_16x16x32_bf16(a, b, c, 0, 0, 0);
}
__device__ __forceinline__ f32x4 mfma16u(u16x8 a, u16x8 b, f32x4 c) {
    return __builtin_amdgcn_mfma_f32_16x16x32_bf16(
        __builtin_bit_cast(bf16x8, a), __builtin_bit_cast(bf16x8, b), c, 0, 0, 0);
}

__device__ __forceinline__ float fexp2(float x) {
    float r;
    asm("v_exp_f32 %0, %1" : "=v"(r) : "v"(x));
    return r;
}

// async global->LDS, 16B per lane, dest = wave-uniform base + lane*16
__device__ __forceinline__ void gload16(const void* g, void* l) {
    __builtin_amdgcn_global_load_lds((const __attribute__((address_space(1))) void*)g,
                                     (__attribute__((address_space(3))) void*)l,
                                     16, 0, 0);
}

// ---- cast + transpose both 1024x1024 weights: W[k][n] -> bf16 Wt[n][k] ----
__global__ __launch_bounds__(256) void cast_transpose2(const float* __restrict__ W0,
                                                       const float* __restrict__ W1,
                                                       __bf16* __restrict__ T0Q,
                                                       __bf16* __restrict__ T1Q) {
    const float* W = blockIdx.z ? W1 : W0;
    __bf16* Wt = blockIdx.z ? T1Q : T0Q;
    __shared__ __bf16 T[64][64];
    const int tid = threadIdx.x;
    const int k0 = blockIdx.y * 64, n0 = blockIdx.x * 64;
#pragma unroll
    for (int c = 0; c < 4; ++c) {
        int idx = c * 256 + tid;
        int kr = idx >> 4, nc = (idx & 15) * 4;
        f32x4 w = *(const f32x4*)&W[(size_t)(k0 + kr) * 1024 + n0 + nc];
        int g = ((nc >> 3) ^ (kr >> 3)) * 8 + (nc & 7);
        bf16x4 pk;
        pk[0] = (__bf16)w[0]; pk[1] = (__bf16)w[1];
        pk[2] = (__bf16)w[2]; pk[3] = (__bf16)w[3];
        *(bf16x4*)&T[kr][g] = pk;
    }
    __syncthreads();
#pragma unroll
    for (int c = 0; c < 2; ++c) {
        int idx = c * 256 + tid;
        int n = idx >> 3, k8 = (idx & 7) * 8;
        bf16x8 o;
#pragma unroll
        for (int e = 0; e < 8; ++e) {
            int k = k8 + e;
            o[e] = T[k][((n >> 3) ^ (k >> 3)) * 8 + (n & 7)];
        }
        *(bf16x8*)&Wt[(size_t)(n0 + n) * 1024 + k0 + k8] = o;
    }
}

// ---------------- GEMM + optional fused fp32->bf16 A-cast + fused V^T epilogue ----------------
template <bool OUT_BF16, bool WRITE_VT, bool CAST_A>
__global__ __launch_bounds__(256) void gemm_bt(const void* __restrict__ Av,
                                               const unsigned short* __restrict__ Bt,
                                               void* __restrict__ Cout,
                                               const float* __restrict__ bias,
                                               __bf16* __restrict__ vT) {
    constexpr int K = 1024, NN = 1024;
    __shared__ unsigned short SM[18432];            // As(128x72) | Bs(128x72); reused as T[128][128]
    typedef unsigned short u16_72[72];
    u16_72* As = (u16_72*)SM;
    u16_72* Bs = (u16_72*)(SM + 9216);
    const int tid  = threadIdx.x;
    const int lane = tid & 63, wid = tid >> 6;
    const int wm = wid >> 1, wn = wid & 1;
    const int i = lane & 15, q8 = (lane >> 4) * 8;
    // XCD-aware: 512 blocks, bijective swizzle; XCD j gets an 8x8 tile band
    const int bid = blockIdx.y * 8 + blockIdx.x;
    const int swz = (bid & 7) * 64 + (bid >> 3);
    const int tm = (swz >> 3) * 128, tn = (swz & 7) * 128;
    const int srow = tid >> 3, scol = (tid & 7) * 8;

    f32x4 acc[4][4] = {};

    for (int k0 = 0; k0 < K; k0 += 64) {
#pragma unroll
        for (int c = 0; c < 4; ++c) {
            int row = c * 32 + srow;
            u16x8 av;
            if constexpr (CAST_A) {
                const float* Af = (const float*)Av;
                const float* p = &Af[(size_t)(tm + row) * K + k0 + scol];
                f32x4 a0 = *(const f32x4*)p;
                f32x4 a1 = *(const f32x4*)(p + 4);
                av[0] = f2bf(a0[0]); av[1] = f2bf(a0[1]);
                av[2] = f2bf(a0[2]); av[3] = f2bf(a0[3]);
                av[4] = f2bf(a1[0]); av[5] = f2bf(a1[1]);
                av[6] = f2bf(a1[2]); av[7] = f2bf(a1[3]);
            } else {
                const unsigned short* Au = (const unsigned short*)Av;
                av = *(const u16x8*)&Au[(size_t)(tm + row) * K + k0 + scol];
            }
            u16x8 bv = *(const u16x8*)&Bt[(size_t)(tn + row) * K + k0 + scol];
            *(u16x8*)&As[row][scol] = av;
            *(u16x8*)&Bs[row][scol] = bv;
        }
        __syncthreads();
#pragma unroll
        for (int ks = 0; ks < 2; ++ks) {
            u16x8 af[4], bfr[4];
#pragma unroll
            for (int m = 0; m < 4; ++m) af[m]  = *(const u16x8*)&As[wm * 64 + m * 16 + i][ks * 32 + q8];
#pragma unroll
            for (int nn = 0; nn < 4; ++nn) bfr[nn] = *(const u16x8*)&Bs[wn * 64 + nn * 16 + i][ks * 32 + q8];
#pragma unroll
            for (int m = 0; m < 4; ++m)
#pragma unroll
                for (int nn = 0; nn < 4; ++nn)
                    acc[m][nn] = mfma16u(af[m], bfr[nn], acc[m][nn]);
        }
        __syncthreads();
    }

    const int r0 = (lane >> 4) * 4;
#pragma unroll
    for (int nn = 0; nn < 4; ++nn) {
        int col = tn + wn * 64 + nn * 16 + i;
        float bv = 0.f;
        if constexpr (!OUT_BF16) bv = bias[col];
#pragma unroll
        for (int m = 0; m < 4; ++m) {
            int rowb = tm + wm * 64 + m * 16 + r0;
#pragma unroll
            for (int r = 0; r < 4; ++r) {
                if constexpr (OUT_BF16)
                    ((unsigned short*)Cout)[(size_t)(rowb + r) * NN + col] = f2bf(acc[m][nn][r]);
                else
                    ((float*)Cout)[(size_t)(rowb + r) * NN + col] = acc[m][nn][r] + bv;
            }
        }
    }

    if constexpr (WRITE_VT) {
        // phase 1: acc -> granule-XOR-swizzled T[128][128] (overwrites As/Bs; all reads done)
        unsigned short* T = SM;
#pragma unroll
        for (int nn = 0; nn < 4; ++nn) {
            const int col = wn * 64 + nn * 16 + i;
            const int g = col >> 3, c7 = col & 7;
#pragma unroll
            for (int m = 0; m < 4; ++m) {
                const int rbase = wm * 64 + m * 16 + r0;        // r0..r0+3 share rbase>>3
                const int rsw = (rbase >> 3) & 15;
#pragma unroll
                for (int r = 0; r < 4; ++r)
                    T[(rbase + r) * 128 + ((g ^ rsw) * 8) + c7] = f2bf(acc[m][nn][r]);
            }
        }
        __syncthreads();
        // phase 2: coalesced 16B writes of vT[head][d][tm..tm+128)
        const size_t vb0 = ((size_t)(tm >> 11) * 16 + (tn >> 6)) * 131072 + (size_t)(tm & 2047);
#pragma unroll
        for (int c = 0; c < 8; ++c) {
            int idx = c * 256 + tid;                 // 0..2047
            int hh = idx >> 10, dd = (idx >> 4) & 63, n8 = (idx & 15) * 8;
            int g = (hh * 64 + dd) >> 3, c7 = dd & 7, rsw = idx & 15;
            u16x8 o;
#pragma unroll
            for (int e = 0; e < 8; ++e)
                o[e] = T[(n8 + e) * 128 + ((g ^ rsw) * 8) + c7];
            *(u16x8*)&vT[vb0 + (size_t)hh * 131072 + (size_t)dd * 2048 + n8] = o;
        }
    }
}

// ---- Flash attention v8: K staged in LDS, V-fragments direct from L2-resident vT ----
__global__ __launch_bounds__(256, 4) void flash_attn8(const __bf16* __restrict__ qkv,
                                                      const __bf16* __restrict__ vT,
                                                      __bf16* __restrict__ attnout) {
    __shared__ __bf16 Ks[2][4096];     // [64 kv-rows][64 d], granule ^= (row&7); 16 KB total

    const int tid = threadIdx.x, lane = tid & 63, wid = tid >> 6;
    const int i = lane & 15, qg = lane >> 4;

    // XCD-aware decode: XCD j gets whole heads; 16 q-tile blocks share a head per XCD
    const int n = blockIdx.x;                 // 0..1023
    const int j = n & 7, t = n >> 3;
    const int head = j * 8 + (t >> 4);        // 0..63
    const int b = head >> 4, h = head & 15;
    const int q0 = (t & 15) * 128;

    const size_t base  = (size_t)b * (2048 * 1024) + (size_t)h * 64;
    const size_t vbase = (size_t)head * (64 * 2048);

    // Q fragments: 2 groups of 16 q-rows, B-operand layout
    bf16x8 qf[2][2];
#pragma unroll
    for (int g = 0; g < 2; ++g) {
        int qrow = q0 + wid * 32 + g * 16 + i;
#pragma unroll
        for (int s = 0; s < 2; ++s)
            qf[g][s] = *(const bf16x8*)&qkv[base + (size_t)qrow * 1024 + s * 32 + qg * 8];
    }

    // K staging source pointers (per-lane, pre-swizzled granule)
    const int r0s = tid >> 3, g0s = tid & 7;
    const __bf16* ksrc0 = &qkv[base + (size_t)r0s * 1024 + (size_t)((g0s ^ (r0s & 7)) * 8)];
    const __bf16* ksrc1 = ksrc0 + 32 * 1024;

    auto STAGE = [&](int buf) {
        gload16(ksrc0, &Ks[buf][wid * 512]);
        gload16(ksrc1, &Ks[buf][2048 + wid * 512]);
        ksrc0 += 64 * 1024; ksrc1 += 64 * 1024;
    };

    // V-fragment row bases: vT[head][d = nf*16+i][k]; lane column offset 4*qg
    const __bf16* vp[4];
#pragma unroll
    for (int nf = 0; nf < 4; ++nf)
        vp[nf] = &vT[vbase + (size_t)(nf * 16 + i) * 2048 + 4 * qg];
    int kvoff = 0;                            // advances 64 per tile

    const float SL2E = 0.18033688f;           // 0.125 * log2(e)
    f32x4 po[2][4] = {};
    f32x4 po5[2]   = {};                      // row-sums l via ones-MFMA
    bf16x8 ones;
#pragma unroll
    for (int e = 0; e < 8; ++e) ones[e] = (__bf16)1.0f;

    // P' = 2^(S*SL2E) with NO max subtraction: the common factor cancels in O/l.
    auto BODY = [&](const __bf16* Kb) {
        // issue V-fragment loads early (L2-resident; consumed ~500 cyc later in PV)
        bf16x4 vlo[2][4], vhi[2][4];
#pragma unroll
        for (int s = 0; s < 2; ++s)
#pragma unroll
            for (int nf = 0; nf < 4; ++nf) {
                vlo[s][nf] = *(const bf16x4*)(vp[nf] + kvoff + 32 * s);
                vhi[s][nf] = *(const bf16x4*)(vp[nf] + kvoff + 32 * s + 16);
            }

        __builtin_amdgcn_s_setprio(1);
        f32x4 st[2][4];
#pragma unroll
        for (int m = 0; m < 4; ++m) {
            bf16x8 kf0 = *(const bf16x8*)&Kb[(m * 16 + i) * 64 + ((qg) ^ (i & 7)) * 8];
            bf16x8 kf1 = *(const bf16x8*)&Kb[(m * 16 + i) * 64 + ((4 + qg) ^ (i & 7)) * 8];
            f32x4 z0 = {}, z1 = {};
            z0 = mfma16(kf0, qf[0][0], z0);
            st[0][m] = mfma16(kf1, qf[0][1], z0);
            z1 = mfma16(kf0, qf[1][0], z1);
            st[1][m] = mfma16(kf1, qf[1][1], z1);
        }
        __builtin_amdgcn_s_setprio(0);

        // softmax numerator: pure per-lane mul+exp+cvt, no reductions, no branches
        bf16x8 pa[2][2];
#pragma unroll
        for (int g = 0; g < 2; ++g) {
#pragma unroll
            for (int m = 0; m < 4; ++m)
#pragma unroll
                for (int r = 0; r < 4; ++r)
                    st[g][m][r] = fexp2(st[g][m][r] * SL2E);

            // A-fragment in place: slot (s,e) <- st[2s + (e>>2)][e&3]
#pragma unroll
            for (int r = 0; r < 4; ++r) {
                pa[g][0][r]     = (__bf16)st[g][0][r];
                pa[g][0][4 + r] = (__bf16)st[g][1][r];
                pa[g][1][r]     = (__bf16)st[g][2][r];
                pa[g][1][4 + r] = (__bf16)st[g][3][r];
            }
        }

        // O += P V  (B-fragment slot e <- V[(2s+(e>>2))*16 + 4qg + (e&3)][d])
        __builtin_amdgcn_s_setprio(1);
#pragma unroll
        for (int s = 0; s < 2; ++s) {
#pragma unroll
            for (int nf = 0; nf < 4; ++nf) {
                bf16x8 vf = __builtin_shufflevector(vlo[s][nf], vhi[s][nf],
                                                    0, 1, 2, 3, 4, 5, 6, 7);
                po[0][nf] = mfma16(pa[0][s], vf, po[0][nf]);
                po[1][nf] = mfma16(pa[1][s], vf, po[1][nf]);
            }
            po5[0] = mfma16(pa[0][s], ones, po5[0]);
            po5[1] = mfma16(pa[1][s], ones, po5[1]);
        }
        __builtin_amdgcn_s_setprio(0);
        kvoff += 64;
    };

    STAGE(0);
    __syncthreads();
    // unrolled x2: compile-time LDS buffer addresses in each body
    for (int kt2 = 0; kt2 < 16; ++kt2) {
        STAGE(1);                        // K tile 2*kt2+1
        BODY(Ks[0]);                     // tile 2*kt2
        __syncthreads();                 // buf1 staged; buf0 free
        if (kt2 < 15) STAGE(0);          // K tile 2*kt2+2
        BODY(Ks[1]);                     // tile 2*kt2+1
        __syncthreads();                 // buf0 staged; buf1 free
    }

    // epilogue: l is in po5 (all q-columns identical) — no shuffles
#pragma unroll
    for (int g = 0; g < 2; ++g) {
        float linv[4];
#pragma unroll
        for (int r = 0; r < 4; ++r) linv[r] = __builtin_amdgcn_rcpf(po5[g][r]);
#pragma unroll
        for (int nf = 0; nf < 4; ++nf)
#pragma unroll
            for (int r = 0; r < 4; ++r) {
                int row = q0 + wid * 32 + g * 16 + qg * 4 + r;
                attnout[base + (size_t)row * 1024 + nf * 16 + i] = (__bf16)(po[g][nf][r] * linv[r]);
            }
    }
}

extern "C" void kernel_launch(void* const* d_in, const int* in_sizes, int n_in,
                              void* d_out, int out_size, void* d_ws, size_t ws_size,
                              hipStream_t stream) {
    const float* x    = (const float*)d_in[0];
    const float* Wqkv = (const float*)d_in[1];
    const float* Wout = (const float*)d_in[2];
    const float* bout = (const float*)d_in[3];
    float* out = (float*)d_out;

    char* ws = (char*)d_ws;
    // [0,16M):  aout (flash W, gemm2 R)
    // [16,32M): qkvb (gemm1 W, flash R)
    // [32,48M): vT  (gemm1 epilogue W, flash R)
    // [48,50M): wqt ; [50,52M): wot
    unsigned short* aout = (unsigned short*)(ws);
    unsigned short* qkvb = (unsigned short*)(ws + (16u << 20));
    __bf16*         vTp  = (__bf16*)(ws + (32u << 20));
    __bf16*         wqt  = (__bf16*)(ws + (48u << 20));
    __bf16*         wot  = (__bf16*)(ws + (50u << 20));

    cast_transpose2<<<dim3(16, 16, 2), 256, 0, stream>>>(Wqkv, Wout, wqt, wot);

    // qkv = bf16(x) @ W_qkv (bf16 out) + fused A-cast + fused per-head V^T
    gemm_bt<true, true, true><<<dim3(8, 64), 256, 0, stream>>>(x, (const unsigned short*)wqt,
                                                               qkvb, nullptr, vTp);

    flash_attn8<<<1024, 256, 0, stream>>>((const __bf16*)qkvb, vTp, (__bf16*)aout);

    // out = attn @ W_out + b (fp32)
    gemm_bt<false, false, false><<<dim3(8, 64), 256, 0, stream>>>(aout, (const unsigned short*)wot,
                                                                  out, bout, nullptr);
}

// Round 11
// 140.661 us; speedup vs baseline: 2.6677x; 2.6677x over previous
//
#include <hip/hip_runtime.h>

typedef float  f32x4  __attribute__((ext_vector_type(4)));
typedef __bf16 bf16x8 __attribute__((ext_vector_type(8)));
typedef __bf16 bf16x4 __attribute__((ext_vector_type(4)));
typedef unsigned short u16x8 __attribute__((ext_vector_type(8)));

__device__ __forceinline__ unsigned short f2bf(float f) {
    unsigned u = __builtin_bit_cast(unsigned, f);
    unsigned r = u + 0x7FFFu + ((u >> 16) & 1u);   // round-to-nearest-even
    return (unsigned short)(r >> 16);
}

__device__ __forceinline__ f32x4 mfma16(bf16x8 a, bf16x8 b, f32x4 c) {
    return __builtin_amdgcn_mfma_f32_16x16x32_bf16(a, b, c, 0, 0, 0);
}
__device__ __forceinline__ f32x4 mfma16u(u16x8 a, u16x8 b, f32x4 c) {
    return __builtin_amdgcn_mfma_f32_16x16x32_bf16(
        __builtin_bit_cast(bf16x8, a), __builtin_bit_cast(bf16x8, b), c, 0, 0, 0);
}

__device__ __forceinline__ float fexp2(float x) {
    float r;
    asm("v_exp_f32 %0, %1" : "=v"(r) : "v"(x));
    return r;
}

// async global->LDS, 16B per lane, dest = wave-uniform base + lane*16
__device__ __forceinline__ void gload16(const void* g, void* l) {
    __builtin_amdgcn_global_load_lds((const __attribute__((address_space(1))) void*)g,
                                     (__attribute__((address_space(3))) void*)l,
                                     16, 0, 0);
}

// ---- cast + transpose both 1024x1024 weights: W[k][n] -> bf16 Wt[n][k] ----
__global__ __launch_bounds__(256) void cast_transpose2(const float* __restrict__ W0,
                                                       const float* __restrict__ W1,
                                                       __bf16* __restrict__ T0Q,
                                                       __bf16* __restrict__ T1Q) {
    const float* W = blockIdx.z ? W1 : W0;
    __bf16* Wt = blockIdx.z ? T1Q : T0Q;
    __shared__ __bf16 T[64][64];
    const int tid = threadIdx.x;
    const int k0 = blockIdx.y * 64, n0 = blockIdx.x * 64;
#pragma unroll
    for (int c = 0; c < 4; ++c) {
        int idx = c * 256 + tid;
        int kr = idx >> 4, nc = (idx & 15) * 4;
        f32x4 w = *(const f32x4*)&W[(size_t)(k0 + kr) * 1024 + n0 + nc];
        int g = ((nc >> 3) ^ (kr >> 3)) * 8 + (nc & 7);
        bf16x4 pk;
        pk[0] = (__bf16)w[0]; pk[1] = (__bf16)w[1];
        pk[2] = (__bf16)w[2]; pk[3] = (__bf16)w[3];
        *(bf16x4*)&T[kr][g] = pk;
    }
    __syncthreads();
#pragma unroll
    for (int c = 0; c < 2; ++c) {
        int idx = c * 256 + tid;
        int n = idx >> 3, k8 = (idx & 7) * 8;
        bf16x8 o;
#pragma unroll
        for (int e = 0; e < 8; ++e) {
            int k = k8 + e;
            o[e] = T[k][((n >> 3) ^ (k >> 3)) * 8 + (n & 7)];
        }
        *(bf16x8*)&Wt[(size_t)(n0 + n) * 1024 + k0 + k8] = o;
    }
}

// -------- GEMM v3: m97-style single-buffer gload_lds staging, 2 barriers/K-step --------
// C[8192][1024] = A[8192][1024] * Bt[1024][1024]^T.
// LDS: As = SM[0..8192), Bs = SM[8192..16384); tile[row][g] holds global granule g^(row&7).
template <bool OUT_BF16, bool WRITE_VT, bool CAST_A>
__global__ __launch_bounds__(256) void gemm_bt(const void* __restrict__ Av,
                                               const unsigned short* __restrict__ Bt,
                                               void* __restrict__ Cout,
                                               const float* __restrict__ bias,
                                               __bf16* __restrict__ vT) {
    constexpr int K = 1024, NN = 1024;
    __shared__ unsigned short SM[16384];   // As(128x64) | Bs(128x64) = 32 KB; reused as T[128][128]
    const int tid  = threadIdx.x;
    const int lane = tid & 63, wid = tid >> 6;
    const int wm = wid >> 1, wn = wid & 1;
    const int i = lane & 15, qg = lane >> 4;
    // XCD-aware: 512 blocks, bijective swizzle; XCD j gets an 8x8 tile band
    const int bid = blockIdx.y * 8 + blockIdx.x;
    const int swz = (bid & 7) * 64 + (bid >> 3);
    const int tm = (swz >> 3) * 128, tn = (swz & 7) * 128;

    // gload staging geometry: instr c covers rows wid*32 + c*8 + (lane>>3), LDS granule lane&7,
    // global granule (lane&7)^(row&7)  [row&7 == (lane>>3)&7, invariant in c]
    const int rl  = wid * 32 + (lane >> 3);
    const int gsw = ((lane & 7) ^ (rl & 7)) * 8;
    const unsigned short* Bsrc = &Bt[(size_t)(tn + rl) * K + gsw];
    const unsigned short* Asrc = &((const unsigned short*)Av)[(size_t)(tm + rl) * K + gsw];
    // CAST_A register staging geometry (rows c*32+srow; row&7 == srow&7)
    const int srow = tid >> 3, scol = (tid & 7) * 8;
    const float* Afsrc = &((const float*)Av)[(size_t)(tm + srow) * K + scol];
    const int acol = ((scol >> 3) ^ (srow & 7)) * 8;

    f32x4 acc[4][4] = {};

    auto STAGE = [&]() {
#pragma unroll
        for (int c = 0; c < 4; ++c) {
            if constexpr (CAST_A) {
                int row = c * 32 + srow;
                const float* p = Afsrc + (size_t)c * 32 * K;
                f32x4 a0 = *(const f32x4*)p;
                f32x4 a1 = *(const f32x4*)(p + 4);
                u16x8 av;
                av[0] = f2bf(a0[0]); av[1] = f2bf(a0[1]);
                av[2] = f2bf(a0[2]); av[3] = f2bf(a0[3]);
                av[4] = f2bf(a1[0]); av[5] = f2bf(a1[1]);
                av[6] = f2bf(a1[2]); av[7] = f2bf(a1[3]);
                *(u16x8*)&SM[row * 64 + acol] = av;
            } else {
                gload16(Asrc + (size_t)c * 8 * K, &SM[(wid * 32 + c * 8) * 64]);
            }
            gload16(Bsrc + (size_t)c * 8 * K, &SM[8192 + (wid * 32 + c * 8) * 64]);
        }
        Afsrc += 64; Asrc += 64; Bsrc += 64;
    };

    auto COMP = [&]() {
        const unsigned short* As = SM;
        const unsigned short* Bs = SM + 8192;
#pragma unroll
        for (int ks = 0; ks < 2; ++ks) {
            u16x8 af[4], bfr[4];
#pragma unroll
            for (int m = 0; m < 4; ++m)
                af[m]  = *(const u16x8*)&As[(wm * 64 + m * 16 + i) * 64 + (((ks * 4 + qg) ^ (i & 7)) * 8)];
#pragma unroll
            for (int nn = 0; nn < 4; ++nn)
                bfr[nn] = *(const u16x8*)&Bs[(wn * 64 + nn * 16 + i) * 64 + (((ks * 4 + qg) ^ (i & 7)) * 8)];
#pragma unroll
            for (int m = 0; m < 4; ++m)
#pragma unroll
                for (int nn = 0; nn < 4; ++nn)
                    acc[m][nn] = mfma16u(af[m], bfr[nn], acc[m][nn]);
        }
    };

    for (int kk = 0; kk < 16; ++kk) {
        STAGE();
        __syncthreads();       // drains gload_lds (vmcnt) + ds_writes (lgkmcnt)
        COMP();
        __syncthreads();       // all reads done before next overwrite
    }

    const int r0 = qg * 4;
#pragma unroll
    for (int nn = 0; nn < 4; ++nn) {
        int col = tn + wn * 64 + nn * 16 + i;
        float bv = 0.f;
        if constexpr (!OUT_BF16) bv = bias[col];
#pragma unroll
        for (int m = 0; m < 4; ++m) {
            int rowb = tm + wm * 64 + m * 16 + r0;
#pragma unroll
            for (int r = 0; r < 4; ++r) {
                if constexpr (OUT_BF16)
                    ((unsigned short*)Cout)[(size_t)(rowb + r) * NN + col] = f2bf(acc[m][nn][r]);
                else
                    ((float*)Cout)[(size_t)(rowb + r) * NN + col] = acc[m][nn][r] + bv;
            }
        }
    }

    if constexpr (WRITE_VT) {
        // phase 1: acc -> granule-XOR-swizzled T[128][128] (reuses all 32 KB; reads done)
        unsigned short* T = SM;
#pragma unroll
        for (int nn = 0; nn < 4; ++nn) {
            const int col = wn * 64 + nn * 16 + i;
            const int g = col >> 3, c7 = col & 7;
#pragma unroll
            for (int m = 0; m < 4; ++m) {
                const int rbase = wm * 64 + m * 16 + r0;        // r0..r0+3 share rbase>>3
                const int rsw = (rbase >> 3) & 15;
#pragma unroll
                for (int r = 0; r < 4; ++r)
                    T[(rbase + r) * 128 + ((g ^ rsw) * 8) + c7] = f2bf(acc[m][nn][r]);
            }
        }
        __syncthreads();
        // phase 2: coalesced 16B writes of vT[head][d][tm..tm+128)
        const size_t vb0 = ((size_t)(tm >> 11) * 16 + (tn >> 6)) * 131072 + (size_t)(tm & 2047);
#pragma unroll
        for (int c = 0; c < 8; ++c) {
            int idx = c * 256 + tid;                 // 0..2047
            int hh = idx >> 10, dd = (idx >> 4) & 63, n8 = (idx & 15) * 8;
            int g = (hh * 64 + dd) >> 3, c7 = dd & 7, rsw = idx & 15;
            u16x8 o;
#pragma unroll
            for (int e = 0; e < 8; ++e)
                o[e] = T[(n8 + e) * 128 + ((g ^ rsw) * 8) + c7];
            *(u16x8*)&vT[vb0 + (size_t)hh * 131072 + (size_t)dd * 2048 + n8] = o;
        }
    }
}

// ---- Flash attention v9: K+V LDS-staged (known-good v7 structure), no-max softmax,
//      Q pre-scaled by SL2E (kills the per-element mul in the hot loop) ----
__global__ __launch_bounds__(256, 4) void flash_attn9(const __bf16* __restrict__ qkv,
                                                      const __bf16* __restrict__ vT,
                                                      __bf16* __restrict__ attnout) {
    __shared__ __bf16 Ks[2][4096];     // [64 kv-rows][64 d], granule ^= (row&7)
    __shared__ __bf16 Vs[2][4096];     // [64 d-rows][64 kv], granule ^= (row&7)

    const int tid = threadIdx.x, lane = tid & 63, wid = tid >> 6;
    const int i = lane & 15, qg = lane >> 4;

    // XCD-aware decode: XCD j gets whole heads
    const int n = blockIdx.x;                 // 0..1023
    const int j = n & 7, t = n >> 3;
    const int head = j * 8 + (t >> 4);        // 0..63
    const int b = head >> 4, h = head & 15;
    const int q0 = (t & 15) * 128;

    const size_t base  = (size_t)b * (2048 * 1024) + (size_t)h * 64;
    const size_t vbase = (size_t)head * (64 * 2048);

    const float SL2E = 0.18033688f;           // 0.125 * log2(e)

    // Q fragments pre-scaled by SL2E (one extra bf16 rounding; S comes out in log2 units)
    bf16x8 qf[2][2];
#pragma unroll
    for (int g = 0; g < 2; ++g) {
        int qrow = q0 + wid * 32 + g * 16 + i;
#pragma unroll
        for (int s = 0; s < 2; ++s) {
            bf16x8 tq = *(const bf16x8*)&qkv[base + (size_t)qrow * 1024 + s * 32 + qg * 8];
#pragma unroll
            for (int e = 0; e < 8; ++e)
                qf[g][s][e] = (__bf16)((float)tq[e] * SL2E);
        }
    }

    // staging source pointers (per-lane, pre-swizzled granule)
    const int r0s = tid >> 3, g0s = tid & 7;
    const __bf16* ksrc0 = &qkv[base + (size_t)r0s * 1024 + (size_t)((g0s ^ (r0s & 7)) * 8)];
    const __bf16* ksrc1 = ksrc0 + 32 * 1024;
    const __bf16* vsrc0 = &vT[vbase + (size_t)r0s * 2048 + (size_t)((g0s ^ (r0s & 7)) * 8)];
    const __bf16* vsrc1 = vsrc0 + 32 * 2048;

    auto STAGE = [&](int buf) {
        gload16(ksrc0, &Ks[buf][wid * 512]);
        gload16(ksrc1, &Ks[buf][2048 + wid * 512]);
        gload16(vsrc0, &Vs[buf][wid * 512]);
        gload16(vsrc1, &Vs[buf][2048 + wid * 512]);
        ksrc0 += 64 * 1024; ksrc1 += 64 * 1024;
        vsrc0 += 64;        vsrc1 += 64;
    };

    f32x4 po[2][4] = {};
    f32x4 po5[2]   = {};                      // row-sums l via ones-MFMA
    bf16x8 ones;
#pragma unroll
    for (int e = 0; e < 8; ++e) ones[e] = (__bf16)1.0f;

    // P' = 2^(S') with NO max subtraction (S' pre-scaled): common factor cancels in O/l.
    auto BODY = [&](const __bf16* Kb, const __bf16* Vb) {
        __builtin_amdgcn_s_setprio(1);
        f32x4 st[2][4];
#pragma unroll
        for (int m = 0; m < 4; ++m) {
            bf16x8 kf0 = *(const bf16x8*)&Kb[(m * 16 + i) * 64 + ((qg) ^ (i & 7)) * 8];
            bf16x8 kf1 = *(const bf16x8*)&Kb[(m * 16 + i) * 64 + ((4 + qg) ^ (i & 7)) * 8];
            f32x4 z0 = {}, z1 = {};
            z0 = mfma16(kf0, qf[0][0], z0);
            st[0][m] = mfma16(kf1, qf[0][1], z0);
            z1 = mfma16(kf0, qf[1][0], z1);
            st[1][m] = mfma16(kf1, qf[1][1], z1);
        }
        __builtin_amdgcn_s_setprio(0);

        // softmax numerator: pure per-lane exp+cvt, no reductions, no branches
        bf16x8 pa[2][2];
#pragma unroll
        for (int g = 0; g < 2; ++g) {
#pragma unroll
            for (int m = 0; m < 4; ++m)
#pragma unroll
                for (int r = 0; r < 4; ++r)
                    st[g][m][r] = fexp2(st[g][m][r]);

            // A-fragment in place: slot (s,e) <- st[2s + (e>>2)][e&3]
#pragma unroll
            for (int r = 0; r < 4; ++r) {
                pa[g][0][r]     = (__bf16)st[g][0][r];
                pa[g][0][4 + r] = (__bf16)st[g][1][r];
                pa[g][1][r]     = (__bf16)st[g][2][r];
                pa[g][1][4 + r] = (__bf16)st[g][3][r];
            }
        }

        // O += P V  (B reads LDS at the matching k-slot permutation)
        __builtin_amdgcn_s_setprio(1);
#pragma unroll
        for (int s = 0; s < 2; ++s) {
#pragma unroll
            for (int nf = 0; nf < 4; ++nf) {
                const int row = nf * 16 + i;
                bf16x8 vf;
                *(bf16x4*)&vf = *(const bf16x4*)
                    &Vb[row * 64 + (((s * 4 + (qg >> 1)) ^ (i & 7)) * 8 + (qg & 1) * 4)];
                *((bf16x4*)&vf + 1) = *(const bf16x4*)
                    &Vb[row * 64 + (((s * 4 + 2 + (qg >> 1)) ^ (i & 7)) * 8 + (qg & 1) * 4)];
                po[0][nf] = mfma16(pa[0][s], vf, po[0][nf]);
                po[1][nf] = mfma16(pa[1][s], vf, po[1][nf]);
            }
            po5[0] = mfma16(pa[0][s], ones, po5[0]);
            po5[1] = mfma16(pa[1][s], ones, po5[1]);
        }
        __builtin_amdgcn_s_setprio(0);
    };

    STAGE(0);
    __syncthreads();
    // unrolled x2: compile-time LDS buffer addresses in each body
    for (int kt2 = 0; kt2 < 16; ++kt2) {
        STAGE(1);                        // tile 2*kt2+1
        BODY(Ks[0], Vs[0]);              // tile 2*kt2
        __syncthreads();                 // buf1 staged; buf0 free
        if (kt2 < 15) STAGE(0);          // tile 2*kt2+2
        BODY(Ks[1], Vs[1]);              // tile 2*kt2+1
        __syncthreads();                 // buf0 staged; buf1 free
    }

    // epilogue: l is in po5 (all q-columns identical) — no shuffles
#pragma unroll
    for (int g = 0; g < 2; ++g) {
        float linv[4];
#pragma unroll
        for (int r = 0; r < 4; ++r) linv[r] = __builtin_amdgcn_rcpf(po5[g][r]);
#pragma unroll
        for (int nf = 0; nf < 4; ++nf)
#pragma unroll
            for (int r = 0; r < 4; ++r) {
                int row = q0 + wid * 32 + g * 16 + qg * 4 + r;
                attnout[base + (size_t)row * 1024 + nf * 16 + i] = (__bf16)(po[g][nf][r] * linv[r]);
            }
    }
}

extern "C" void kernel_launch(void* const* d_in, const int* in_sizes, int n_in,
                              void* d_out, int out_size, void* d_ws, size_t ws_size,
                              hipStream_t stream) {
    const float* x    = (const float*)d_in[0];
    const float* Wqkv = (const float*)d_in[1];
    const float* Wout = (const float*)d_in[2];
    const float* bout = (const float*)d_in[3];
    float* out = (float*)d_out;

    char* ws = (char*)d_ws;
    // [0,16M):  aout (flash W, gemm2 R)
    // [16,32M): qkvb (gemm1 W, flash R)
    // [32,48M): vT  (gemm1 epilogue W, flash R)
    // [48,50M): wqt ; [50,52M): wot
    unsigned short* aout = (unsigned short*)(ws);
    unsigned short* qkvb = (unsigned short*)(ws + (16u << 20));
    __bf16*         vTp  = (__bf16*)(ws + (32u << 20));
    __bf16*         wqt  = (__bf16*)(ws + (48u << 20));
    __bf16*         wot  = (__bf16*)(ws + (50u << 20));

    cast_transpose2<<<dim3(16, 16, 2), 256, 0, stream>>>(Wqkv, Wout, wqt, wot);

    // qkv = bf16(x) @ W_qkv (bf16 out) + fused A-cast + fused per-head V^T
    gemm_bt<true, true, true><<<dim3(8, 64), 256, 0, stream>>>(x, (const unsigned short*)wqt,
                                                               qkvb, nullptr, vTp);

    flash_attn9<<<1024, 256, 0, stream>>>((const __bf16*)qkvb, vTp, (__bf16*)aout);

    // out = attn @ W_out + b (fp32)
    gemm_bt<false, false, false><<<dim3(8, 64), 256, 0, stream>>>(aout, (const unsigned short*)wot,
                                                                  out, bout, nullptr);
}

// Round 12
// 136.855 us; speedup vs baseline: 2.7419x; 1.0278x over previous
//
#include <hip/hip_runtime.h>

typedef float  f32x4  __attribute__((ext_vector_type(4)));
typedef __bf16 bf16x8 __attribute__((ext_vector_type(8)));
typedef __bf16 bf16x4 __attribute__((ext_vector_type(4)));
typedef unsigned short u16x8 __attribute__((ext_vector_type(8)));

__device__ __forceinline__ unsigned short f2bf(float f) {
    unsigned u = __builtin_bit_cast(unsigned, f);
    unsigned r = u + 0x7FFFu + ((u >> 16) & 1u);   // round-to-nearest-even
    return (unsigned short)(r >> 16);
}

__device__ __forceinline__ f32x4 mfma16(bf16x8 a, bf16x8 b, f32x4 c) {
    return __builtin_amdgcn_mfma_f32_16x16x32_bf16(a, b, c, 0, 0, 0);
}
__device__ __forceinline__ f32x4 mfma16u(u16x8 a, u16x8 b, f32x4 c) {
    return __builtin_amdgcn_mfma_f32_16x16x32_bf16(
        __builtin_bit_cast(bf16x8, a), __builtin_bit_cast(bf16x8, b), c, 0, 0, 0);
}

__device__ __forceinline__ float fexp2(float x) {
    float r;
    asm("v_exp_f32 %0, %1" : "=v"(r) : "v"(x));
    return r;
}

// async global->LDS, 16B per lane, dest = wave-uniform base + lane*16
__device__ __forceinline__ void gload16(const void* g, void* l) {
    __builtin_amdgcn_global_load_lds((const __attribute__((address_space(1))) void*)g,
                                     (__attribute__((address_space(3))) void*)l,
                                     16, 0, 0);
}

// ---- cast + transpose both 1024x1024 weights: W[k][n] -> bf16 Wt[n][k] ----
__global__ __launch_bounds__(256) void cast_transpose2(const float* __restrict__ W0,
                                                       const float* __restrict__ W1,
                                                       __bf16* __restrict__ T0Q,
                                                       __bf16* __restrict__ T1Q) {
    const float* W = blockIdx.z ? W1 : W0;
    __bf16* Wt = blockIdx.z ? T1Q : T0Q;
    __shared__ __bf16 T[64][64];
    const int tid = threadIdx.x;
    const int k0 = blockIdx.y * 64, n0 = blockIdx.x * 64;
#pragma unroll
    for (int c = 0; c < 4; ++c) {
        int idx = c * 256 + tid;
        int kr = idx >> 4, nc = (idx & 15) * 4;
        f32x4 w = *(const f32x4*)&W[(size_t)(k0 + kr) * 1024 + n0 + nc];
        int g = ((nc >> 3) ^ (kr >> 3)) * 8 + (nc & 7);
        bf16x4 pk;
        pk[0] = (__bf16)w[0]; pk[1] = (__bf16)w[1];
        pk[2] = (__bf16)w[2]; pk[3] = (__bf16)w[3];
        *(bf16x4*)&T[kr][g] = pk;
    }
    __syncthreads();
#pragma unroll
    for (int c = 0; c < 2; ++c) {
        int idx = c * 256 + tid;
        int n = idx >> 3, k8 = (idx & 7) * 8;
        bf16x8 o;
#pragma unroll
        for (int e = 0; e < 8; ++e) {
            int k = k8 + e;
            o[e] = T[k][((n >> 3) ^ (k >> 3)) * 8 + (n & 7)];
        }
        *(bf16x8*)&Wt[(size_t)(n0 + n) * 1024 + k0 + k8] = o;
    }
}

// ---- GEMM v4: DOUBLE-buffered gload_lds staging, issue-early/drain-late (flash schedule) ----
// C[8192][1024] = A[8192][1024] * Bt[1024][1024]^T.
// SM: buffer b at [b*16384, +16384): As 8192 | Bs 8192. tile[row][g] = global granule g^(row&7).
template <bool OUT_BF16, bool WRITE_VT, bool CAST_A>
__global__ __launch_bounds__(256) void gemm_bt(const void* __restrict__ Av,
                                               const unsigned short* __restrict__ Bt,
                                               void* __restrict__ Cout,
                                               const float* __restrict__ bias,
                                               __bf16* __restrict__ vT) {
    constexpr int K = 1024, NN = 1024;
    __shared__ unsigned short SM[32768];   // 64 KB: 2 buffers; T[128][128] reuses [0,16384)
    const int tid  = threadIdx.x;
    const int lane = tid & 63, wid = tid >> 6;
    const int wm = wid >> 1, wn = wid & 1;
    const int i = lane & 15, qg = lane >> 4;
    // XCD-aware: 512 blocks, bijective swizzle; XCD j gets an 8x8 tile band
    const int bid = blockIdx.y * 8 + blockIdx.x;
    const int swz = (bid & 7) * 64 + (bid >> 3);
    const int tm = (swz >> 3) * 128, tn = (swz & 7) * 128;

    // gload staging geometry: instr c covers rows wid*32 + c*8 + (lane>>3);
    // LDS granule lane&7 holds global granule (lane&7)^(row&7)   [row&7 == (lane>>3)&7]
    const int rl  = wid * 32 + (lane >> 3);
    const int gsw = ((lane & 7) ^ (rl & 7)) * 8;
    const unsigned short* Bsrc = &Bt[(size_t)(tn + rl) * K + gsw];
    const unsigned short* Asrc = &((const unsigned short*)Av)[(size_t)(tm + rl) * K + gsw];
    // CAST_A register staging geometry (rows c*32+srow; row&7 == srow&7)
    const int srow = tid >> 3, scol = (tid & 7) * 8;
    const float* Afsrc = &((const float*)Av)[(size_t)(tm + srow) * K + scol];
    const int acol = ((scol >> 3) ^ (srow & 7)) * 8;

    f32x4 acc[4][4] = {};
    f32x4 areg[4][2];                      // CAST_A in-flight tile (T14 issue-early)

    auto LOADA = [&](int t) {              // issue fp32 A loads for K-step t
#pragma unroll
        for (int c = 0; c < 4; ++c) {
            const float* p = Afsrc + (size_t)t * 64 + (size_t)c * 32 * K;
            areg[c][0] = *(const f32x4*)p;
            areg[c][1] = *(const f32x4*)(p + 4);
        }
    };
    auto WRITEA = [&](int buf) {           // convert + LDS-write (after COMP: latency hidden)
        unsigned short* dst = &SM[buf * 16384];
#pragma unroll
        for (int c = 0; c < 4; ++c) {
            u16x8 av;
            av[0] = f2bf(areg[c][0][0]); av[1] = f2bf(areg[c][0][1]);
            av[2] = f2bf(areg[c][0][2]); av[3] = f2bf(areg[c][0][3]);
            av[4] = f2bf(areg[c][1][0]); av[5] = f2bf(areg[c][1][1]);
            av[6] = f2bf(areg[c][1][2]); av[7] = f2bf(areg[c][1][3]);
            *(u16x8*)&dst[(c * 32 + srow) * 64 + acol] = av;
        }
    };
    auto STAGE = [&](int t, int buf) {     // async gloads for K-step t into buffer buf
        unsigned short* dst = &SM[buf * 16384];
        if constexpr (!CAST_A) {
#pragma unroll
            for (int c = 0; c < 4; ++c)
                gload16(Asrc + (size_t)t * 64 + (size_t)c * 8 * K, &dst[(wid * 32 + c * 8) * 64]);
        }
#pragma unroll
        for (int c = 0; c < 4; ++c)
            gload16(Bsrc + (size_t)t * 64 + (size_t)c * 8 * K, &dst[8192 + (wid * 32 + c * 8) * 64]);
    };
    auto COMP = [&](int buf) {
        const unsigned short* As = &SM[buf * 16384];
        const unsigned short* Bs = As + 8192;
#pragma unroll
        for (int ks = 0; ks < 2; ++ks) {
            u16x8 af[4], bfr[4];
#pragma unroll
            for (int m = 0; m < 4; ++m)
                af[m]  = *(const u16x8*)&As[(wm * 64 + m * 16 + i) * 64 + (((ks * 4 + qg) ^ (i & 7)) * 8)];
#pragma unroll
            for (int nn = 0; nn < 4; ++nn)
                bfr[nn] = *(const u16x8*)&Bs[(wn * 64 + nn * 16 + i) * 64 + (((ks * 4 + qg) ^ (i & 7)) * 8)];
#pragma unroll
            for (int m = 0; m < 4; ++m)
#pragma unroll
                for (int nn = 0; nn < 4; ++nn)
                    acc[m][nn] = mfma16u(af[m], bfr[nn], acc[m][nn]);
        }
    };

    // prologue: fill buffer 0 (latency exposed once)
    if constexpr (CAST_A) LOADA(0);
    STAGE(0, 0);
    if constexpr (CAST_A) WRITEA(0);
    __syncthreads();
    for (int kk = 0; kk < 16; ++kk) {
        if (kk < 15) {
            if constexpr (CAST_A) LOADA(kk + 1);      // issue early...
            STAGE(kk + 1, (kk + 1) & 1);              // ...overlaps COMP below
        }
        COMP(kk & 1);
        if (kk < 15) {
            if constexpr (CAST_A) WRITEA((kk + 1) & 1);  // loads landed under COMP
        }
        __syncthreads();       // drains vmcnt+lgkmcnt: next buffer fully staged
    }

    const int r0 = qg * 4;
#pragma unroll
    for (int nn = 0; nn < 4; ++nn) {
        int col = tn + wn * 64 + nn * 16 + i;
        float bv = 0.f;
        if constexpr (!OUT_BF16) bv = bias[col];
#pragma unroll
        for (int m = 0; m < 4; ++m) {
            int rowb = tm + wm * 64 + m * 16 + r0;
#pragma unroll
            for (int r = 0; r < 4; ++r) {
                if constexpr (OUT_BF16)
                    ((unsigned short*)Cout)[(size_t)(rowb + r) * NN + col] = f2bf(acc[m][nn][r]);
                else
                    ((float*)Cout)[(size_t)(rowb + r) * NN + col] = acc[m][nn][r] + bv;
            }
        }
    }

    if constexpr (WRITE_VT) {
        // phase 1: acc -> granule-XOR-swizzled T[128][128] in SM[0,16384)
        // (final COMP read buffer 1 = SM[16384,32768); the K-loop's last barrier ordered all)
        unsigned short* T = SM;
#pragma unroll
        for (int nn = 0; nn < 4; ++nn) {
            const int col = wn * 64 + nn * 16 + i;
            const int g = col >> 3, c7 = col & 7;
#pragma unroll
            for (int m = 0; m < 4; ++m) {
                const int rbase = wm * 64 + m * 16 + r0;        // r0..r0+3 share rbase>>3
                const int rsw = (rbase >> 3) & 15;
#pragma unroll
                for (int r = 0; r < 4; ++r)
                    T[(rbase + r) * 128 + ((g ^ rsw) * 8) + c7] = f2bf(acc[m][nn][r]);
            }
        }
        __syncthreads();
        // phase 2: coalesced 16B writes of vT[head][d][tm..tm+128)
        const size_t vb0 = ((size_t)(tm >> 11) * 16 + (tn >> 6)) * 131072 + (size_t)(tm & 2047);
#pragma unroll
        for (int c = 0; c < 8; ++c) {
            int idx = c * 256 + tid;                 // 0..2047
            int hh = idx >> 10, dd = (idx >> 4) & 63, n8 = (idx & 15) * 8;
            int g = (hh * 64 + dd) >> 3, c7 = dd & 7, rsw = idx & 15;
            u16x8 o;
#pragma unroll
            for (int e = 0; e < 8; ++e)
                o[e] = T[(n8 + e) * 128 + ((g ^ rsw) * 8) + c7];
            *(u16x8*)&vT[vb0 + (size_t)hh * 131072 + (size_t)dd * 2048 + n8] = o;
        }
    }
}

// ---- Flash attention v9 (unchanged, known-good 78.2 us): K+V LDS-staged, no-max softmax,
//      Q pre-scaled by SL2E ----
__global__ __launch_bounds__(256, 4) void flash_attn9(const __bf16* __restrict__ qkv,
                                                      const __bf16* __restrict__ vT,
                                                      __bf16* __restrict__ attnout) {
    __shared__ __bf16 Ks[2][4096];     // [64 kv-rows][64 d], granule ^= (row&7)
    __shared__ __bf16 Vs[2][4096];     // [64 d-rows][64 kv], granule ^= (row&7)

    const int tid = threadIdx.x, lane = tid & 63, wid = tid >> 6;
    const int i = lane & 15, qg = lane >> 4;

    // XCD-aware decode: XCD j gets whole heads
    const int n = blockIdx.x;                 // 0..1023
    const int j = n & 7, t = n >> 3;
    const int head = j * 8 + (t >> 4);        // 0..63
    const int b = head >> 4, h = head & 15;
    const int q0 = (t & 15) * 128;

    const size_t base  = (size_t)b * (2048 * 1024) + (size_t)h * 64;
    const size_t vbase = (size_t)head * (64 * 2048);

    const float SL2E = 0.18033688f;           // 0.125 * log2(e)

    // Q fragments pre-scaled by SL2E (one extra bf16 rounding; S comes out in log2 units)
    bf16x8 qf[2][2];
#pragma unroll
    for (int g = 0; g < 2; ++g) {
        int qrow = q0 + wid * 32 + g * 16 + i;
#pragma unroll
        for (int s = 0; s < 2; ++s) {
            bf16x8 tq = *(const bf16x8*)&qkv[base + (size_t)qrow * 1024 + s * 32 + qg * 8];
#pragma unroll
            for (int e = 0; e < 8; ++e)
                qf[g][s][e] = (__bf16)((float)tq[e] * SL2E);
        }
    }

    // staging source pointers (per-lane, pre-swizzled granule)
    const int r0s = tid >> 3, g0s = tid & 7;
    const __bf16* ksrc0 = &qkv[base + (size_t)r0s * 1024 + (size_t)((g0s ^ (r0s & 7)) * 8)];
    const __bf16* ksrc1 = ksrc0 + 32 * 1024;
    const __bf16* vsrc0 = &vT[vbase + (size_t)r0s * 2048 + (size_t)((g0s ^ (r0s & 7)) * 8)];
    const __bf16* vsrc1 = vsrc0 + 32 * 2048;

    auto STAGE = [&](int buf) {
        gload16(ksrc0, &Ks[buf][wid * 512]);
        gload16(ksrc1, &Ks[buf][2048 + wid * 512]);
        gload16(vsrc0, &Vs[buf][wid * 512]);
        gload16(vsrc1, &Vs[buf][2048 + wid * 512]);
        ksrc0 += 64 * 1024; ksrc1 += 64 * 1024;
        vsrc0 += 64;        vsrc1 += 64;
    };

    f32x4 po[2][4] = {};
    f32x4 po5[2]   = {};                      // row-sums l via ones-MFMA
    bf16x8 ones;
#pragma unroll
    for (int e = 0; e < 8; ++e) ones[e] = (__bf16)1.0f;

    // P' = 2^(S') with NO max subtraction (S' pre-scaled): common factor cancels in O/l.
    auto BODY = [&](const __bf16* Kb, const __bf16* Vb) {
        __builtin_amdgcn_s_setprio(1);
        f32x4 st[2][4];
#pragma unroll
        for (int m = 0; m < 4; ++m) {
            bf16x8 kf0 = *(const bf16x8*)&Kb[(m * 16 + i) * 64 + ((qg) ^ (i & 7)) * 8];
            bf16x8 kf1 = *(const bf16x8*)&Kb[(m * 16 + i) * 64 + ((4 + qg) ^ (i & 7)) * 8];
            f32x4 z0 = {}, z1 = {};
            z0 = mfma16(kf0, qf[0][0], z0);
            st[0][m] = mfma16(kf1, qf[0][1], z0);
            z1 = mfma16(kf0, qf[1][0], z1);
            st[1][m] = mfma16(kf1, qf[1][1], z1);
        }
        __builtin_amdgcn_s_setprio(0);

        // softmax numerator: pure per-lane exp+cvt, no reductions, no branches
        bf16x8 pa[2][2];
#pragma unroll
        for (int g = 0; g < 2; ++g) {
#pragma unroll
            for (int m = 0; m < 4; ++m)
#pragma unroll
                for (int r = 0; r < 4; ++r)
                    st[g][m][r] = fexp2(st[g][m][r]);

            // A-fragment in place: slot (s,e) <- st[2s + (e>>2)][e&3]
#pragma unroll
            for (int r = 0; r < 4; ++r) {
                pa[g][0][r]     = (__bf16)st[g][0][r];
                pa[g][0][4 + r] = (__bf16)st[g][1][r];
                pa[g][1][r]     = (__bf16)st[g][2][r];
                pa[g][1][4 + r] = (__bf16)st[g][3][r];
            }
        }

        // O += P V  (B reads LDS at the matching k-slot permutation)
        __builtin_amdgcn_s_setprio(1);
#pragma unroll
        for (int s = 0; s < 2; ++s) {
#pragma unroll
            for (int nf = 0; nf < 4; ++nf) {
                const int row = nf * 16 + i;
                bf16x8 vf;
                *(bf16x4*)&vf = *(const bf16x4*)
                    &Vb[row * 64 + (((s * 4 + (qg >> 1)) ^ (i & 7)) * 8 + (qg & 1) * 4)];
                *((bf16x4*)&vf + 1) = *(const bf16x4*)
                    &Vb[row * 64 + (((s * 4 + 2 + (qg >> 1)) ^ (i & 7)) * 8 + (qg & 1) * 4)];
                po[0][nf] = mfma16(pa[0][s], vf, po[0][nf]);
                po[1][nf] = mfma16(pa[1][s], vf, po[1][nf]);
            }
            po5[0] = mfma16(pa[0][s], ones, po5[0]);
            po5[1] = mfma16(pa[1][s], ones, po5[1]);
        }
        __builtin_amdgcn_s_setprio(0);
    };

    STAGE(0);
    __syncthreads();
    // unrolled x2: compile-time LDS buffer addresses in each body
    for (int kt2 = 0; kt2 < 16; ++kt2) {
        STAGE(1);                        // tile 2*kt2+1
        BODY(Ks[0], Vs[0]);              // tile 2*kt2
        __syncthreads();                 // buf1 staged; buf0 free
        if (kt2 < 15) STAGE(0);          // tile 2*kt2+2
        BODY(Ks[1], Vs[1]);              // tile 2*kt2+1
        __syncthreads();                 // buf0 staged; buf1 free
    }

    // epilogue: l is in po5 (all q-columns identical) — no shuffles
#pragma unroll
    for (int g = 0; g < 2; ++g) {
        float linv[4];
#pragma unroll
        for (int r = 0; r < 4; ++r) linv[r] = __builtin_amdgcn_rcpf(po5[g][r]);
#pragma unroll
        for (int nf = 0; nf < 4; ++nf)
#pragma unroll
            for (int r = 0; r < 4; ++r) {
                int row = q0 + wid * 32 + g * 16 + qg * 4 + r;
                attnout[base + (size_t)row * 1024 + nf * 16 + i] = (__bf16)(po[g][nf][r] * linv[r]);
            }
    }
}

extern "C" void kernel_launch(void* const* d_in, const int* in_sizes, int n_in,
                              void* d_out, int out_size, void* d_ws, size_t ws_size,
                              hipStream_t stream) {
    const float* x    = (const float*)d_in[0];
    const float* Wqkv = (const float*)d_in[1];
    const float* Wout = (const float*)d_in[2];
    const float* bout = (const float*)d_in[3];
    float* out = (float*)d_out;

    char* ws = (char*)d_ws;
    // [0,16M):  aout (flash W, gemm2 R)
    // [16,32M): qkvb (gemm1 W, flash R)
    // [32,48M): vT  (gemm1 epilogue W, flash R)
    // [48,50M): wqt ; [50,52M): wot
    unsigned short* aout = (unsigned short*)(ws);
    unsigned short* qkvb = (unsigned short*)(ws + (16u << 20));
    __bf16*         vTp  = (__bf16*)(ws + (32u << 20));
    __bf16*         wqt  = (__bf16*)(ws + (48u << 20));
    __bf16*         wot  = (__bf16*)(ws + (50u << 20));

    cast_transpose2<<<dim3(16, 16, 2), 256, 0, stream>>>(Wqkv, Wout, wqt, wot);

    // qkv = bf16(x) @ W_qkv (bf16 out) + fused A-cast + fused per-head V^T
    gemm_bt<true, true, true><<<dim3(8, 64), 256, 0, stream>>>(x, (const unsigned short*)wqt,
                                                               qkvb, nullptr, vTp);

    flash_attn9<<<1024, 256, 0, stream>>>((const __bf16*)qkvb, vTp, (__bf16*)aout);

    // out = attn @ W_out + b (fp32)
    gemm_bt<false, false, false><<<dim3(8, 64), 256, 0, stream>>>(aout, (const unsigned short*)wot,
                                                                  out, bout, nullptr);
}

// Round 13
// 128.598 us; speedup vs baseline: 2.9179x; 1.0642x over previous
//
#include <hip/hip_runtime.h>

typedef float  f32x4  __attribute__((ext_vector_type(4)));
typedef __bf16 bf16x8 __attribute__((ext_vector_type(8)));
typedef __bf16 bf16x4 __attribute__((ext_vector_type(4)));
typedef unsigned short u16x8 __attribute__((ext_vector_type(8)));

__device__ __forceinline__ unsigned short f2bf(float f) {
    unsigned u = __builtin_bit_cast(unsigned, f);
    unsigned r = u + 0x7FFFu + ((u >> 16) & 1u);   // round-to-nearest-even
    return (unsigned short)(r >> 16);
}

__device__ __forceinline__ f32x4 mfma16(bf16x8 a, bf16x8 b, f32x4 c) {
    return __builtin_amdgcn_mfma_f32_16x16x32_bf16(a, b, c, 0, 0, 0);
}
__device__ __forceinline__ f32x4 mfma16u(u16x8 a, u16x8 b, f32x4 c) {
    return __builtin_amdgcn_mfma_f32_16x16x32_bf16(
        __builtin_bit_cast(bf16x8, a), __builtin_bit_cast(bf16x8, b), c, 0, 0, 0);
}

__device__ __forceinline__ float fexp2(float x) {
    float r;
    asm("v_exp_f32 %0, %1" : "=v"(r) : "v"(x));
    return r;
}

// async global->LDS, 16B per lane, dest = wave-uniform base + lane*16
__device__ __forceinline__ void gload16(const void* g, void* l) {
    __builtin_amdgcn_global_load_lds((const __attribute__((address_space(1))) void*)g,
                                     (__attribute__((address_space(3))) void*)l,
                                     16, 0, 0);
}

// ---- cast + transpose both 1024x1024 weights: W[k][n] -> bf16 Wt[n][k] ----
__global__ __launch_bounds__(256) void cast_transpose2(const float* __restrict__ W0,
                                                       const float* __restrict__ W1,
                                                       __bf16* __restrict__ T0Q,
                                                       __bf16* __restrict__ T1Q) {
    const float* W = blockIdx.z ? W1 : W0;
    __bf16* Wt = blockIdx.z ? T1Q : T0Q;
    __shared__ __bf16 T[64][64];
    const int tid = threadIdx.x;
    const int k0 = blockIdx.y * 64, n0 = blockIdx.x * 64;
#pragma unroll
    for (int c = 0; c < 4; ++c) {
        int idx = c * 256 + tid;
        int kr = idx >> 4, nc = (idx & 15) * 4;
        f32x4 w = *(const f32x4*)&W[(size_t)(k0 + kr) * 1024 + n0 + nc];
        int g = ((nc >> 3) ^ (kr >> 3)) * 8 + (nc & 7);
        bf16x4 pk;
        pk[0] = (__bf16)w[0]; pk[1] = (__bf16)w[1];
        pk[2] = (__bf16)w[2]; pk[3] = (__bf16)w[3];
        *(bf16x4*)&T[kr][g] = pk;
    }
    __syncthreads();
#pragma unroll
    for (int c = 0; c < 2; ++c) {
        int idx = c * 256 + tid;
        int n = idx >> 3, k8 = (idx & 7) * 8;
        bf16x8 o;
#pragma unroll
        for (int e = 0; e < 8; ++e) {
            int k = k8 + e;
            o[e] = T[k][((n >> 3) ^ (k >> 3)) * 8 + (n & 7)];
        }
        *(bf16x8*)&Wt[(size_t)(n0 + n) * 1024 + k0 + k8] = o;
    }
}

// ---- GEMM v4: double-buffered gload_lds staging, issue-early/drain-late ----
// C[8192][1024] = A[8192][1024] * Bt[1024][1024]^T.
// SM: buffer b at [b*16384, +16384): As 8192 | Bs 8192. tile[row][g] = global granule g^(row&7).
// WRITE_VT emits vT with PERMUTED kv-axis: p = 32s+8qg+4u+r holds token kv = 32s+16u+4qg+r,
// so flash PV B-fragments are 8 contiguous elems at granule s*4+qg (single ds_read_b128).
template <bool OUT_BF16, bool WRITE_VT, bool CAST_A>
__global__ __launch_bounds__(256) void gemm_bt(const void* __restrict__ Av,
                                               const unsigned short* __restrict__ Bt,
                                               void* __restrict__ Cout,
                                               const float* __restrict__ bias,
                                               __bf16* __restrict__ vT) {
    constexpr int K = 1024, NN = 1024;
    __shared__ unsigned short SM[32768];   // 64 KB: 2 buffers; T[128][128] reuses [0,16384)
    const int tid  = threadIdx.x;
    const int lane = tid & 63, wid = tid >> 6;
    const int wm = wid >> 1, wn = wid & 1;
    const int i = lane & 15, qg = lane >> 4;
    // XCD-aware: 512 blocks, bijective swizzle; XCD j gets an 8x8 tile band
    const int bid = blockIdx.y * 8 + blockIdx.x;
    const int swz = (bid & 7) * 64 + (bid >> 3);
    const int tm = (swz >> 3) * 128, tn = (swz & 7) * 128;

    // gload staging geometry: instr c covers rows wid*32 + c*8 + (lane>>3);
    // LDS granule lane&7 holds global granule (lane&7)^(row&7)   [row&7 == (lane>>3)&7]
    const int rl  = wid * 32 + (lane >> 3);
    const int gsw = ((lane & 7) ^ (rl & 7)) * 8;
    const unsigned short* Bsrc = &Bt[(size_t)(tn + rl) * K + gsw];
    const unsigned short* Asrc = &((const unsigned short*)Av)[(size_t)(tm + rl) * K + gsw];
    // CAST_A register staging geometry (rows c*32+srow; row&7 == srow&7)
    const int srow = tid >> 3, scol = (tid & 7) * 8;
    const float* Afsrc = &((const float*)Av)[(size_t)(tm + srow) * K + scol];
    const int acol = ((scol >> 3) ^ (srow & 7)) * 8;

    f32x4 acc[4][4] = {};
    f32x4 areg[4][2];                      // CAST_A in-flight tile (issue-early)

    auto LOADA = [&](int t) {
#pragma unroll
        for (int c = 0; c < 4; ++c) {
            const float* p = Afsrc + (size_t)t * 64 + (size_t)c * 32 * K;
            areg[c][0] = *(const f32x4*)p;
            areg[c][1] = *(const f32x4*)(p + 4);
        }
    };
    auto WRITEA = [&](int buf) {
        unsigned short* dst = &SM[buf * 16384];
#pragma unroll
        for (int c = 0; c < 4; ++c) {
            u16x8 av;
            av[0] = f2bf(areg[c][0][0]); av[1] = f2bf(areg[c][0][1]);
            av[2] = f2bf(areg[c][0][2]); av[3] = f2bf(areg[c][0][3]);
            av[4] = f2bf(areg[c][1][0]); av[5] = f2bf(areg[c][1][1]);
            av[6] = f2bf(areg[c][1][2]); av[7] = f2bf(areg[c][1][3]);
            *(u16x8*)&dst[(c * 32 + srow) * 64 + acol] = av;
        }
    };
    auto STAGE = [&](int t, int buf) {
        unsigned short* dst = &SM[buf * 16384];
        if constexpr (!CAST_A) {
#pragma unroll
            for (int c = 0; c < 4; ++c)
                gload16(Asrc + (size_t)t * 64 + (size_t)c * 8 * K, &dst[(wid * 32 + c * 8) * 64]);
        }
#pragma unroll
        for (int c = 0; c < 4; ++c)
            gload16(Bsrc + (size_t)t * 64 + (size_t)c * 8 * K, &dst[8192 + (wid * 32 + c * 8) * 64]);
    };
    auto COMP = [&](int buf) {
        const unsigned short* As = &SM[buf * 16384];
        const unsigned short* Bs = As + 8192;
#pragma unroll
        for (int ks = 0; ks < 2; ++ks) {
            u16x8 af[4], bfr[4];
#pragma unroll
            for (int m = 0; m < 4; ++m)
                af[m]  = *(const u16x8*)&As[(wm * 64 + m * 16 + i) * 64 + (((ks * 4 + qg) ^ (i & 7)) * 8)];
#pragma unroll
            for (int nn = 0; nn < 4; ++nn)
                bfr[nn] = *(const u16x8*)&Bs[(wn * 64 + nn * 16 + i) * 64 + (((ks * 4 + qg) ^ (i & 7)) * 8)];
#pragma unroll
            for (int m = 0; m < 4; ++m)
#pragma unroll
                for (int nn = 0; nn < 4; ++nn)
                    acc[m][nn] = mfma16u(af[m], bfr[nn], acc[m][nn]);
        }
    };

    // prologue: fill buffer 0 (latency exposed once)
    if constexpr (CAST_A) LOADA(0);
    STAGE(0, 0);
    if constexpr (CAST_A) WRITEA(0);
    __syncthreads();
#pragma unroll 2
    for (int kk = 0; kk < 16; ++kk) {
        if (kk < 15) {
            if constexpr (CAST_A) LOADA(kk + 1);      // issue early...
            STAGE(kk + 1, (kk + 1) & 1);              // ...overlaps COMP below
        }
        COMP(kk & 1);
        if (kk < 15) {
            if constexpr (CAST_A) WRITEA((kk + 1) & 1);  // loads landed under COMP
        }
        __syncthreads();       // drains vmcnt+lgkmcnt: next buffer fully staged
    }

    const int r0 = qg * 4;
#pragma unroll
    for (int nn = 0; nn < 4; ++nn) {
        int col = tn + wn * 64 + nn * 16 + i;
        float bv = 0.f;
        if constexpr (!OUT_BF16) bv = bias[col];
#pragma unroll
        for (int m = 0; m < 4; ++m) {
            int rowb = tm + wm * 64 + m * 16 + r0;
#pragma unroll
            for (int r = 0; r < 4; ++r) {
                if constexpr (OUT_BF16)
                    ((unsigned short*)Cout)[(size_t)(rowb + r) * NN + col] = f2bf(acc[m][nn][r]);
                else
                    ((float*)Cout)[(size_t)(rowb + r) * NN + col] = acc[m][nn][r] + bv;
            }
        }
    }

    if constexpr (WRITE_VT) {
        // phase 1: acc -> granule-XOR-swizzled T[128][128] in SM[0,16384)
        unsigned short* T = SM;
#pragma unroll
        for (int nn = 0; nn < 4; ++nn) {
            const int col = wn * 64 + nn * 16 + i;
            const int g = col >> 3, c7 = col & 7;
#pragma unroll
            for (int m = 0; m < 4; ++m) {
                const int rbase = wm * 64 + m * 16 + r0;        // r0..r0+3 share rbase>>3
                const int rsw = (rbase >> 3) & 15;
#pragma unroll
                for (int r = 0; r < 4; ++r)
                    T[(rbase + r) * 128 + ((g ^ rsw) * 8) + c7] = f2bf(acc[m][nn][r]);
            }
        }
        __syncthreads();
        // phase 2: coalesced 16B writes of vT'[head][d][p], p = kv-permuted:
        // granule g_ = blk*8 + s*4 + qg ; element e -> token l = blk*64+32s+16(e>>2)+4qg+(e&3)
        const size_t vb0 = ((size_t)(tm >> 11) * 16 + (tn >> 6)) * 131072 + (size_t)(tm & 2047);
#pragma unroll
        for (int c = 0; c < 8; ++c) {
            int idx = c * 256 + tid;                 // 0..2047
            int hh = idx >> 10, dd = (idx >> 4) & 63;
            int g_ = idx & 15;
            int blk = g_ >> 3, gk = g_ & 7, sv = gk >> 2, qv = gk & 3;
            int cg = (hh * 64 + dd) >> 3, c7 = dd & 7;
            u16x8 o;
#pragma unroll
            for (int e = 0; e < 8; ++e) {
                int l = blk * 64 + sv * 32 + (e >> 2) * 16 + qv * 4 + (e & 3);
                int rsw = (l >> 3) & 15;
                o[e] = T[l * 128 + ((cg ^ rsw) * 8) + c7];
            }
            *(u16x8*)&vT[vb0 + (size_t)hh * 131072 + (size_t)dd * 2048 + g_ * 8] = o;
        }
    }
}

// ---- Flash attention v10: v9 + kv-permuted vT' -> PV B-fragments via single ds_read_b128 ----
__global__ __launch_bounds__(256, 4) void flash_attn10(const __bf16* __restrict__ qkv,
                                                       const __bf16* __restrict__ vT,
                                                       __bf16* __restrict__ attnout) {
    __shared__ __bf16 Ks[2][4096];     // [64 kv-rows][64 d], granule ^= (row&7)
    __shared__ __bf16 Vs[2][4096];     // [64 d-rows][64 kv'], granule ^= (row&7)

    const int tid = threadIdx.x, lane = tid & 63, wid = tid >> 6;
    const int i = lane & 15, qg = lane >> 4;

    // XCD-aware decode: XCD j gets whole heads
    const int n = blockIdx.x;                 // 0..1023
    const int j = n & 7, t = n >> 3;
    const int head = j * 8 + (t >> 4);        // 0..63
    const int b = head >> 4, h = head & 15;
    const int q0 = (t & 15) * 128;

    const size_t base  = (size_t)b * (2048 * 1024) + (size_t)h * 64;
    const size_t vbase = (size_t)head * (64 * 2048);

    const float SL2E = 0.18033688f;           // 0.125 * log2(e)

    // Q fragments pre-scaled by SL2E
    bf16x8 qf[2][2];
#pragma unroll
    for (int g = 0; g < 2; ++g) {
        int qrow = q0 + wid * 32 + g * 16 + i;
#pragma unroll
        for (int s = 0; s < 2; ++s) {
            bf16x8 tq = *(const bf16x8*)&qkv[base + (size_t)qrow * 1024 + s * 32 + qg * 8];
#pragma unroll
            for (int e = 0; e < 8; ++e)
                qf[g][s][e] = (__bf16)((float)tq[e] * SL2E);
        }
    }

    // staging source pointers (per-lane, pre-swizzled granule)
    const int r0s = tid >> 3, g0s = tid & 7;
    const __bf16* ksrc0 = &qkv[base + (size_t)r0s * 1024 + (size_t)((g0s ^ (r0s & 7)) * 8)];
    const __bf16* ksrc1 = ksrc0 + 32 * 1024;
    const __bf16* vsrc0 = &vT[vbase + (size_t)r0s * 2048 + (size_t)((g0s ^ (r0s & 7)) * 8)];
    const __bf16* vsrc1 = vsrc0 + 32 * 2048;

    auto STAGE = [&](int buf) {
        gload16(ksrc0, &Ks[buf][wid * 512]);
        gload16(ksrc1, &Ks[buf][2048 + wid * 512]);
        gload16(vsrc0, &Vs[buf][wid * 512]);
        gload16(vsrc1, &Vs[buf][2048 + wid * 512]);
        ksrc0 += 64 * 1024; ksrc1 += 64 * 1024;
        vsrc0 += 64;        vsrc1 += 64;
    };

    f32x4 po[2][4] = {};
    f32x4 po5[2]   = {};                      // row-sums l via ones-MFMA
    bf16x8 ones;
#pragma unroll
    for (int e = 0; e < 8; ++e) ones[e] = (__bf16)1.0f;

    // P' = 2^(S') with NO max subtraction (S' pre-scaled): common factor cancels in O/l.
    auto BODY = [&](const __bf16* Kb, const __bf16* Vb) {
        __builtin_amdgcn_s_setprio(1);
        f32x4 st[2][4];
#pragma unroll
        for (int m = 0; m < 4; ++m) {
            bf16x8 kf0 = *(const bf16x8*)&Kb[(m * 16 + i) * 64 + ((qg) ^ (i & 7)) * 8];
            bf16x8 kf1 = *(const bf16x8*)&Kb[(m * 16 + i) * 64 + ((4 + qg) ^ (i & 7)) * 8];
            f32x4 z0 = {}, z1 = {};
            z0 = mfma16(kf0, qf[0][0], z0);
            st[0][m] = mfma16(kf1, qf[0][1], z0);
            z1 = mfma16(kf0, qf[1][0], z1);
            st[1][m] = mfma16(kf1, qf[1][1], z1);
        }
        __builtin_amdgcn_s_setprio(0);

        // softmax numerator: pure per-lane exp+cvt, no reductions, no branches
        bf16x8 pa[2][2];
#pragma unroll
        for (int g = 0; g < 2; ++g) {
#pragma unroll
            for (int m = 0; m < 4; ++m)
#pragma unroll
                for (int r = 0; r < 4; ++r)
                    st[g][m][r] = fexp2(st[g][m][r]);

            // A-fragment in place: slot (s,e) <- st[2s + (e>>2)][e&3]
#pragma unroll
            for (int r = 0; r < 4; ++r) {
                pa[g][0][r]     = (__bf16)st[g][0][r];
                pa[g][0][4 + r] = (__bf16)st[g][1][r];
                pa[g][1][r]     = (__bf16)st[g][2][r];
                pa[g][1][4 + r] = (__bf16)st[g][3][r];
            }
        }

        // O += P V : vT' permutation makes slot run contiguous -> single b128, kf-form swizzle
        __builtin_amdgcn_s_setprio(1);
#pragma unroll
        for (int s = 0; s < 2; ++s) {
#pragma unroll
            for (int nf = 0; nf < 4; ++nf) {
                bf16x8 vf = *(const bf16x8*)&Vb[(nf * 16 + i) * 64 + (((s * 4 + qg) ^ (i & 7)) * 8)];
                po[0][nf] = mfma16(pa[0][s], vf, po[0][nf]);
                po[1][nf] = mfma16(pa[1][s], vf, po[1][nf]);
            }
            po5[0] = mfma16(pa[0][s], ones, po5[0]);
            po5[1] = mfma16(pa[1][s], ones, po5[1]);
        }
        __builtin_amdgcn_s_setprio(0);
    };

    STAGE(0);
    __syncthreads();
    // unrolled x2: compile-time LDS buffer addresses in each body
    for (int kt2 = 0; kt2 < 16; ++kt2) {
        STAGE(1);                        // tile 2*kt2+1
        BODY(Ks[0], Vs[0]);              // tile 2*kt2
        __syncthreads();                 // buf1 staged; buf0 free
        if (kt2 < 15) STAGE(0);          // tile 2*kt2+2
        BODY(Ks[1], Vs[1]);              // tile 2*kt2+1
        __syncthreads();                 // buf0 staged; buf1 free
    }

    // epilogue: l is in po5 (all q-columns identical) — no shuffles
#pragma unroll
    for (int g = 0; g < 2; ++g) {
        float linv[4];
#pragma unroll
        for (int r = 0; r < 4; ++r) linv[r] = __builtin_amdgcn_rcpf(po5[g][r]);
#pragma unroll
        for (int nf = 0; nf < 4; ++nf)
#pragma unroll
            for (int r = 0; r < 4; ++r) {
                int row = q0 + wid * 32 + g * 16 + qg * 4 + r;
                attnout[base + (size_t)row * 1024 + nf * 16 + i] = (__bf16)(po[g][nf][r] * linv[r]);
            }
    }
}

extern "C" void kernel_launch(void* const* d_in, const int* in_sizes, int n_in,
                              void* d_out, int out_size, void* d_ws, size_t ws_size,
                              hipStream_t stream) {
    const float* x    = (const float*)d_in[0];
    const float* Wqkv = (const float*)d_in[1];
    const float* Wout = (const float*)d_in[2];
    const float* bout = (const float*)d_in[3];
    float* out = (float*)d_out;

    char* ws = (char*)d_ws;
    // [0,16M):  aout (flash W, gemm2 R)
    // [16,32M): qkvb (gemm1 W, flash R)
    // [32,48M): vT' (gemm1 epilogue W, flash R; kv-permuted)
    // [48,50M): wqt ; [50,52M): wot
    unsigned short* aout = (unsigned short*)(ws);
    unsigned short* qkvb = (unsigned short*)(ws + (16u << 20));
    __bf16*         vTp  = (__bf16*)(ws + (32u << 20));
    __bf16*         wqt  = (__bf16*)(ws + (48u << 20));
    __bf16*         wot  = (__bf16*)(ws + (50u << 20));

    cast_transpose2<<<dim3(16, 16, 2), 256, 0, stream>>>(Wqkv, Wout, wqt, wot);

    // qkv = bf16(x) @ W_qkv (bf16 out) + fused A-cast + fused per-head permuted V^T
    gemm_bt<true, true, true><<<dim3(8, 64), 256, 0, stream>>>(x, (const unsigned short*)wqt,
                                                               qkvb, nullptr, vTp);

    flash_attn10<<<1024, 256, 0, stream>>>((const __bf16*)qkvb, vTp, (__bf16*)aout);

    // out = attn @ W_out + b (fp32)
    gemm_bt<false, false, false><<<dim3(8, 64), 256, 0, stream>>>(aout, (const unsigned short*)wot,
                                                                  out, bout, nullptr);
}

// Round 14
// 128.127 us; speedup vs baseline: 2.9287x; 1.0037x over previous
//
#include <hip/hip_runtime.h>

typedef float  f32x4  __attribute__((ext_vector_type(4)));
typedef __bf16 bf16x8 __attribute__((ext_vector_type(8)));
typedef __bf16 bf16x4 __attribute__((ext_vector_type(4)));
typedef unsigned short u16x8 __attribute__((ext_vector_type(8)));

__device__ __forceinline__ unsigned short f2bf(float f) {
    unsigned u = __builtin_bit_cast(unsigned, f);
    unsigned r = u + 0x7FFFu + ((u >> 16) & 1u);   // round-to-nearest-even
    return (unsigned short)(r >> 16);
}

__device__ __forceinline__ f32x4 mfma16(bf16x8 a, bf16x8 b, f32x4 c) {
    return __builtin_amdgcn_mfma_f32_16x16x32_bf16(a, b, c, 0, 0, 0);
}
__device__ __forceinline__ f32x4 mfma16u(u16x8 a, u16x8 b, f32x4 c) {
    return __builtin_amdgcn_mfma_f32_16x16x32_bf16(
        __builtin_bit_cast(bf16x8, a), __builtin_bit_cast(bf16x8, b), c, 0, 0, 0);
}

__device__ __forceinline__ float fexp2(float x) {
    float r;
    asm("v_exp_f32 %0, %1" : "=v"(r) : "v"(x));
    return r;
}

// async global->LDS, 16B per lane, dest = wave-uniform base + lane*16
__device__ __forceinline__ void gload16(const void* g, void* l) {
    __builtin_amdgcn_global_load_lds((const __attribute__((address_space(1))) void*)g,
                                     (__attribute__((address_space(3))) void*)l,
                                     16, 0, 0);
}

// ---- cast + transpose both 1024x1024 weights: W[k][n] -> bf16 Wt[n][k] ----
__global__ __launch_bounds__(256) void cast_transpose2(const float* __restrict__ W0,
                                                       const float* __restrict__ W1,
                                                       __bf16* __restrict__ T0Q,
                                                       __bf16* __restrict__ T1Q) {
    const float* W = blockIdx.z ? W1 : W0;
    __bf16* Wt = blockIdx.z ? T1Q : T0Q;
    __shared__ __bf16 T[64][64];
    const int tid = threadIdx.x;
    const int k0 = blockIdx.y * 64, n0 = blockIdx.x * 64;
#pragma unroll
    for (int c = 0; c < 4; ++c) {
        int idx = c * 256 + tid;
        int kr = idx >> 4, nc = (idx & 15) * 4;
        f32x4 w = *(const f32x4*)&W[(size_t)(k0 + kr) * 1024 + n0 + nc];
        int g = ((nc >> 3) ^ (kr >> 3)) * 8 + (nc & 7);
        bf16x4 pk;
        pk[0] = (__bf16)w[0]; pk[1] = (__bf16)w[1];
        pk[2] = (__bf16)w[2]; pk[3] = (__bf16)w[3];
        *(bf16x4*)&T[kr][g] = pk;
    }
    __syncthreads();
#pragma unroll
    for (int c = 0; c < 2; ++c) {
        int idx = c * 256 + tid;
        int n = idx >> 3, k8 = (idx & 7) * 8;
        bf16x8 o;
#pragma unroll
        for (int e = 0; e < 8; ++e) {
            int k = k8 + e;
            o[e] = T[k][((n >> 3) ^ (k >> 3)) * 8 + (n & 7)];
        }
        *(bf16x8*)&Wt[(size_t)(n0 + n) * 1024 + k0 + k8] = o;
    }
}

// ---- GEMM v4: double-buffered gload_lds staging, issue-early/drain-late ----
// C[8192][1024] = A[8192][1024] * Bt[1024][1024]^T.
// SM: buffer b at [b*16384, +16384): As 8192 | Bs 8192. tile[row][g] = global granule g^(row&7).
// WRITE_VT emits vT with PERMUTED kv-axis: p = 32s+8qg+4u+r holds token kv = 32s+16u+4qg+r,
// so flash PV B-fragments are 8 contiguous elems at granule s*4+qg (single ds_read_b128).
template <bool OUT_BF16, bool WRITE_VT, bool CAST_A>
__global__ __launch_bounds__(256) void gemm_bt(const void* __restrict__ Av,
                                               const unsigned short* __restrict__ Bt,
                                               void* __restrict__ Cout,
                                               const float* __restrict__ bias,
                                               __bf16* __restrict__ vT) {
    constexpr int K = 1024, NN = 1024;
    __shared__ unsigned short SM[32768];   // 64 KB: 2 buffers; T[128][128] reuses [0,16384)
    const int tid  = threadIdx.x;
    const int lane = tid & 63, wid = tid >> 6;
    const int wm = wid >> 1, wn = wid & 1;
    const int i = lane & 15, qg = lane >> 4;
    // XCD-aware: 512 blocks, bijective swizzle; XCD j gets an 8x8 tile band
    const int bid = blockIdx.y * 8 + blockIdx.x;
    const int swz = (bid & 7) * 64 + (bid >> 3);
    const int tm = (swz >> 3) * 128, tn = (swz & 7) * 128;

    // gload staging geometry: instr c covers rows wid*32 + c*8 + (lane>>3);
    // LDS granule lane&7 holds global granule (lane&7)^(row&7)   [row&7 == (lane>>3)&7]
    const int rl  = wid * 32 + (lane >> 3);
    const int gsw = ((lane & 7) ^ (rl & 7)) * 8;
    const unsigned short* Bsrc = &Bt[(size_t)(tn + rl) * K + gsw];
    const unsigned short* Asrc = &((const unsigned short*)Av)[(size_t)(tm + rl) * K + gsw];
    // CAST_A register staging geometry (rows c*32+srow; row&7 == srow&7)
    const int srow = tid >> 3, scol = (tid & 7) * 8;
    const float* Afsrc = &((const float*)Av)[(size_t)(tm + srow) * K + scol];
    const int acol = ((scol >> 3) ^ (srow & 7)) * 8;

    f32x4 acc[4][4] = {};
    f32x4 areg[4][2];                      // CAST_A in-flight tile (issue-early)

    auto LOADA = [&](int t) {
#pragma unroll
        for (int c = 0; c < 4; ++c) {
            const float* p = Afsrc + (size_t)t * 64 + (size_t)c * 32 * K;
            areg[c][0] = *(const f32x4*)p;
            areg[c][1] = *(const f32x4*)(p + 4);
        }
    };
    auto WRITEA = [&](int buf) {
        unsigned short* dst = &SM[buf * 16384];
#pragma unroll
        for (int c = 0; c < 4; ++c) {
            u16x8 av;
            av[0] = f2bf(areg[c][0][0]); av[1] = f2bf(areg[c][0][1]);
            av[2] = f2bf(areg[c][0][2]); av[3] = f2bf(areg[c][0][3]);
            av[4] = f2bf(areg[c][1][0]); av[5] = f2bf(areg[c][1][1]);
            av[6] = f2bf(areg[c][1][2]); av[7] = f2bf(areg[c][1][3]);
            *(u16x8*)&dst[(c * 32 + srow) * 64 + acol] = av;
        }
    };
    auto STAGE = [&](int t, int buf) {
        unsigned short* dst = &SM[buf * 16384];
        if constexpr (!CAST_A) {
#pragma unroll
            for (int c = 0; c < 4; ++c)
                gload16(Asrc + (size_t)t * 64 + (size_t)c * 8 * K, &dst[(wid * 32 + c * 8) * 64]);
        }
#pragma unroll
        for (int c = 0; c < 4; ++c)
            gload16(Bsrc + (size_t)t * 64 + (size_t)c * 8 * K, &dst[8192 + (wid * 32 + c * 8) * 64]);
    };
    auto COMP = [&](int buf) {
        const unsigned short* As = &SM[buf * 16384];
        const unsigned short* Bs = As + 8192;
#pragma unroll
        for (int ks = 0; ks < 2; ++ks) {
            u16x8 af[4], bfr[4];
#pragma unroll
            for (int m = 0; m < 4; ++m)
                af[m]  = *(const u16x8*)&As[(wm * 64 + m * 16 + i) * 64 + (((ks * 4 + qg) ^ (i & 7)) * 8)];
#pragma unroll
            for (int nn = 0; nn < 4; ++nn)
                bfr[nn] = *(const u16x8*)&Bs[(wn * 64 + nn * 16 + i) * 64 + (((ks * 4 + qg) ^ (i & 7)) * 8)];
#pragma unroll
            for (int m = 0; m < 4; ++m)
#pragma unroll
                for (int nn = 0; nn < 4; ++nn)
                    acc[m][nn] = mfma16u(af[m], bfr[nn], acc[m][nn]);
        }
    };

    // prologue: fill buffer 0 (latency exposed once)
    if constexpr (CAST_A) LOADA(0);
    STAGE(0, 0);
    if constexpr (CAST_A) WRITEA(0);
    __syncthreads();
#pragma unroll 2
    for (int kk = 0; kk < 16; ++kk) {
        if (kk < 15) {
            if constexpr (CAST_A) LOADA(kk + 1);      // issue early...
            STAGE(kk + 1, (kk + 1) & 1);              // ...overlaps COMP below
        }
        COMP(kk & 1);
        if (kk < 15) {
            if constexpr (CAST_A) WRITEA((kk + 1) & 1);  // loads landed under COMP
        }
        __syncthreads();       // drains vmcnt+lgkmcnt: next buffer fully staged
    }

    const int r0 = qg * 4;
#pragma unroll
    for (int nn = 0; nn < 4; ++nn) {
        int col = tn + wn * 64 + nn * 16 + i;
        float bv = 0.f;
        if constexpr (!OUT_BF16) bv = bias[col];
#pragma unroll
        for (int m = 0; m < 4; ++m) {
            int rowb = tm + wm * 64 + m * 16 + r0;
#pragma unroll
            for (int r = 0; r < 4; ++r) {
                if constexpr (OUT_BF16)
                    ((unsigned short*)Cout)[(size_t)(rowb + r) * NN + col] = f2bf(acc[m][nn][r]);
                else
                    ((float*)Cout)[(size_t)(rowb + r) * NN + col] = acc[m][nn][r] + bv;
            }
        }
    }

    if constexpr (WRITE_VT) {
        // phase 1: acc -> granule-XOR-swizzled T[128][128] in SM[0,16384)
        unsigned short* T = SM;
#pragma unroll
        for (int nn = 0; nn < 4; ++nn) {
            const int col = wn * 64 + nn * 16 + i;
            const int g = col >> 3, c7 = col & 7;
#pragma unroll
            for (int m = 0; m < 4; ++m) {
                const int rbase = wm * 64 + m * 16 + r0;        // r0..r0+3 share rbase>>3
                const int rsw = (rbase >> 3) & 15;
#pragma unroll
                for (int r = 0; r < 4; ++r)
                    T[(rbase + r) * 128 + ((g ^ rsw) * 8) + c7] = f2bf(acc[m][nn][r]);
            }
        }
        __syncthreads();
        // phase 2: coalesced 16B writes of vT'[head][d][p], p = kv-permuted:
        // granule g_ = blk*8 + s*4 + qg ; element e -> token l = blk*64+32s+16(e>>2)+4qg+(e&3)
        const size_t vb0 = ((size_t)(tm >> 11) * 16 + (tn >> 6)) * 131072 + (size_t)(tm & 2047);
#pragma unroll
        for (int c = 0; c < 8; ++c) {
            int idx = c * 256 + tid;                 // 0..2047
            int hh = idx >> 10, dd = (idx >> 4) & 63;
            int g_ = idx & 15;
            int blk = g_ >> 3, gk = g_ & 7, sv = gk >> 2, qv = gk & 3;
            int cg = (hh * 64 + dd) >> 3, c7 = dd & 7;
            u16x8 o;
#pragma unroll
            for (int e = 0; e < 8; ++e) {
                int l = blk * 64 + sv * 32 + (e >> 2) * 16 + qv * 4 + (e & 3);
                int rsw = (l >> 3) & 15;
                o[e] = T[l * 128 + ((cg ^ rsw) * 8) + c7];
            }
            *(u16x8*)&vT[vb0 + (size_t)hh * 131072 + (size_t)dd * 2048 + g_ * 8] = o;
        }
    }
}

// ---- Flash attention v10: v9 + kv-permuted vT' -> PV B-fragments via single ds_read_b128 ----
__global__ __launch_bounds__(256, 4) void flash_attn10(const __bf16* __restrict__ qkv,
                                                       const __bf16* __restrict__ vT,
                                                       __bf16* __restrict__ attnout) {
    __shared__ __bf16 Ks[2][4096];     // [64 kv-rows][64 d], granule ^= (row&7)
    __shared__ __bf16 Vs[2][4096];     // [64 d-rows][64 kv'], granule ^= (row&7)

    const int tid = threadIdx.x, lane = tid & 63, wid = tid >> 6;
    const int i = lane & 15, qg = lane >> 4;

    // XCD-aware decode: XCD j gets whole heads
    const int n = blockIdx.x;                 // 0..1023
    const int j = n & 7, t = n >> 3;
    const int head = j * 8 + (t >> 4);        // 0..63
    const int b = head >> 4, h = head & 15;
    const int q0 = (t & 15) * 128;

    const size_t base  = (size_t)b * (2048 * 1024) + (size_t)h * 64;
    const size_t vbase = (size_t)head * (64 * 2048);

    const float SL2E = 0.18033688f;           // 0.125 * log2(e)

    // Q fragments pre-scaled by SL2E
    bf16x8 qf[2][2];
#pragma unroll
    for (int g = 0; g < 2; ++g) {
        int qrow = q0 + wid * 32 + g * 16 + i;
#pragma unroll
        for (int s = 0; s < 2; ++s) {
            bf16x8 tq = *(const bf16x8*)&qkv[base + (size_t)qrow * 1024 + s * 32 + qg * 8];
#pragma unroll
            for (int e = 0; e < 8; ++e)
                qf[g][s][e] = (__bf16)((float)tq[e] * SL2E);
        }
    }

    // staging source pointers (per-lane, pre-swizzled granule)
    const int r0s = tid >> 3, g0s = tid & 7;
    const __bf16* ksrc0 = &qkv[base + (size_t)r0s * 1024 + (size_t)((g0s ^ (r0s & 7)) * 8)];
    const __bf16* ksrc1 = ksrc0 + 32 * 1024;
    const __bf16* vsrc0 = &vT[vbase + (size_t)r0s * 2048 + (size_t)((g0s ^ (r0s & 7)) * 8)];
    const __bf16* vsrc1 = vsrc0 + 32 * 2048;

    auto STAGE = [&](int buf) {
        gload16(ksrc0, &Ks[buf][wid * 512]);
        gload16(ksrc1, &Ks[buf][2048 + wid * 512]);
        gload16(vsrc0, &Vs[buf][wid * 512]);
        gload16(vsrc1, &Vs[buf][2048 + wid * 512]);
        ksrc0 += 64 * 1024; ksrc1 += 64 * 1024;
        vsrc0 += 64;        vsrc1 += 64;
    };

    f32x4 po[2][4] = {};
    f32x4 po5[2]   = {};                      // row-sums l via ones-MFMA
    bf16x8 ones;
#pragma unroll
    for (int e = 0; e < 8; ++e) ones[e] = (__bf16)1.0f;

    // P' = 2^(S') with NO max subtraction (S' pre-scaled): common factor cancels in O/l.
    auto BODY = [&](const __bf16* Kb, const __bf16* Vb) {
        __builtin_amdgcn_s_setprio(1);
        f32x4 st[2][4];
#pragma unroll
        for (int m = 0; m < 4; ++m) {
            bf16x8 kf0 = *(const bf16x8*)&Kb[(m * 16 + i) * 64 + ((qg) ^ (i & 7)) * 8];
            bf16x8 kf1 = *(const bf16x8*)&Kb[(m * 16 + i) * 64 + ((4 + qg) ^ (i & 7)) * 8];
            f32x4 z0 = {}, z1 = {};
            z0 = mfma16(kf0, qf[0][0], z0);
            st[0][m] = mfma16(kf1, qf[0][1], z0);
            z1 = mfma16(kf0, qf[1][0], z1);
            st[1][m] = mfma16(kf1, qf[1][1], z1);
        }
        __builtin_amdgcn_s_setprio(0);

        // softmax numerator: pure per-lane exp+cvt, no reductions, no branches
        bf16x8 pa[2][2];
#pragma unroll
        for (int g = 0; g < 2; ++g) {
#pragma unroll
            for (int m = 0; m < 4; ++m)
#pragma unroll
                for (int r = 0; r < 4; ++r)
                    st[g][m][r] = fexp2(st[g][m][r]);

            // A-fragment in place: slot (s,e) <- st[2s + (e>>2)][e&3]
#pragma unroll
            for (int r = 0; r < 4; ++r) {
                pa[g][0][r]     = (__bf16)st[g][0][r];
                pa[g][0][4 + r] = (__bf16)st[g][1][r];
                pa[g][1][r]     = (__bf16)st[g][2][r];
                pa[g][1][4 + r] = (__bf16)st[g][3][r];
            }
        }

        // O += P V : vT' permutation makes slot run contiguous -> single b128, kf-form swizzle
        __builtin_amdgcn_s_setprio(1);
#pragma unroll
        for (int s = 0; s < 2; ++s) {
#pragma unroll
            for (int nf = 0; nf < 4; ++nf) {
                bf16x8 vf = *(const bf16x8*)&Vb[(nf * 16 + i) * 64 + (((s * 4 + qg) ^ (i & 7)) * 8)];
                po[0][nf] = mfma16(pa[0][s], vf, po[0][nf]);
                po[1][nf] = mfma16(pa[1][s], vf, po[1][nf]);
            }
            po5[0] = mfma16(pa[0][s], ones, po5[0]);
            po5[1] = mfma16(pa[1][s], ones, po5[1]);
        }
        __builtin_amdgcn_s_setprio(0);
    };

    STAGE(0);
    __syncthreads();
    // unrolled x2: compile-time LDS buffer addresses in each body
    for (int kt2 = 0; kt2 < 16; ++kt2) {
        STAGE(1);                        // tile 2*kt2+1
        BODY(Ks[0], Vs[0]);              // tile 2*kt2
        __syncthreads();                 // buf1 staged; buf0 free
        if (kt2 < 15) STAGE(0);          // tile 2*kt2+2
        BODY(Ks[1], Vs[1]);              // tile 2*kt2+1
        __syncthreads();                 // buf0 staged; buf1 free
    }

    // epilogue: l is in po5 (all q-columns identical) — no shuffles
#pragma unroll
    for (int g = 0; g < 2; ++g) {
        float linv[4];
#pragma unroll
        for (int r = 0; r < 4; ++r) linv[r] = __builtin_amdgcn_rcpf(po5[g][r]);
#pragma unroll
        for (int nf = 0; nf < 4; ++nf)
#pragma unroll
            for (int r = 0; r < 4; ++r) {
                int row = q0 + wid * 32 + g * 16 + qg * 4 + r;
                attnout[base + (size_t)row * 1024 + nf * 16 + i] = (__bf16)(po[g][nf][r] * linv[r]);
            }
    }
}

extern "C" void kernel_launch(void* const* d_in, const int* in_sizes, int n_in,
                              void* d_out, int out_size, void* d_ws, size_t ws_size,
                              hipStream_t stream) {
    const float* x    = (const float*)d_in[0];
    const float* Wqkv = (const float*)d_in[1];
    const float* Wout = (const float*)d_in[2];
    const float* bout = (const float*)d_in[3];
    float* out = (float*)d_out;

    char* ws = (char*)d_ws;
    // [0,16M):  aout (flash W, gemm2 R)
    // [16,32M): qkvb (gemm1 W, flash R)
    // [32,48M): vT' (gemm1 epilogue W, flash R; kv-permuted)
    // [48,50M): wqt ; [50,52M): wot
    unsigned short* aout = (unsigned short*)(ws);
    unsigned short* qkvb = (unsigned short*)(ws + (16u << 20));
    __bf16*         vTp  = (__bf16*)(ws + (32u << 20));
    __bf16*         wqt  = (__bf16*)(ws + (48u << 20));
    __bf16*         wot  = (__bf16*)(ws + (50u << 20));

    cast_transpose2<<<dim3(16, 16, 2), 256, 0, stream>>>(Wqkv, Wout, wqt, wot);

    // qkv = bf16(x) @ W_qkv (bf16 out) + fused A-cast + fused per-head permuted V^T
    gemm_bt<true, true, true><<<dim3(8, 64), 256, 0, stream>>>(x, (const unsigned short*)wqt,
                                                               qkvb, nullptr, vTp);

    flash_attn10<<<1024, 256, 0, stream>>>((const __bf16*)qkvb, vTp, (__bf16*)aout);

    // out = attn @ W_out + b (fp32)
    gemm_bt<false, false, false><<<dim3(8, 64), 256, 0, stream>>>(aout, (const unsigned short*)wot,
                                                                  out, bout, nullptr);
}